// Round 12
// baseline (1704.963 us; speedup 1.0000x reference)
//
#include <hip/hip_runtime.h>
#include <hip/hip_fp16.h>
#include <math.h>

typedef __bf16 bf16x8 __attribute__((ext_vector_type(8)));
typedef float  f32x4  __attribute__((ext_vector_type(4)));

#define AH  264              // act plane stride (bf16); 132 dw % 32 == 4 -> 2-way only (free)
#define TOT 589824           // staged weight elems (hi); lo at +TOT

// staged ws layout (bf16, [n][k] transposed, zero-padded K tails)
#define OFF_W0T   0          // [256][64]
#define OFF_WHT   16384      // 4 x [256][256]
#define OFF_W5AT  278528     // [256][256]
#define OFF_W5BT  344064     // [256][64]
#define OFF_W6T   360448     // [256][256]
#define OFF_W7T   425984     // [256][256]
#define OFF_WFT   491520     // [256][256]
#define OFF_WMAT  557056     // [128][256]

__global__ void prep_weights(const float* __restrict__ W0, const float* __restrict__ Wh,
                             const float* __restrict__ W5, const float* __restrict__ W6,
                             const float* __restrict__ W7, const float* __restrict__ Wf,
                             const float* __restrict__ Wm, __bf16* __restrict__ ws) {
  int idx = blockIdx.x * blockDim.x + threadIdx.x;
  if (idx >= TOT) return;
  float v = 0.f;
  if (idx < OFF_WHT)        { int j = idx;            int n=j>>6, k=j&63;   v = (k<60)? W0[k*256+n] : 0.f; }
  else if (idx < OFF_W5AT)  { int j = idx - OFF_WHT;  int i=j>>16, r=j&65535, n=r>>8, k=r&255; v = Wh[i*65536+k*256+n]; }
  else if (idx < OFF_W5BT)  { int j = idx - OFF_W5AT; int n=j>>8, k=j&255;  v = W5[k*256+n]; }
  else if (idx < OFF_W6T)   { int j = idx - OFF_W5BT; int n=j>>6, k=j&63;   v = (k<60)? W5[(256+k)*256+n] : 0.f; }
  else if (idx < OFF_W7T)   { int j = idx - OFF_W6T;  int n=j>>8, k=j&255;  v = W6[k*256+n]; }
  else if (idx < OFF_WFT)   { int j = idx - OFF_W7T;  int n=j>>8, k=j&255;  v = W7[k*256+n]; }
  else if (idx < OFF_WMAT)  { int j = idx - OFF_WFT;  int n=j>>8, k=j&255;  v = Wf[k*256+n]; }
  else                      { int j = idx - OFF_WMAT; int n=j>>8, k=j&255;  v = Wm[k*128+n]; }
  __bf16 hi = (__bf16)v;
  ws[idx] = hi;
  ws[TOT + idx] = (__bf16)(v - (float)hi);
}

// ---- split-bf16 3-pass MFMA layer; act = hi/lo bf16 planes in LDS ----
// 1024 threads = 16 waves. wave w: mBase=(w>>3)*64 (4 m-tiles, 2 m-groups),
// nBase=(w&7)*NT*16 (8 n-groups). In-place: compute -> barrier -> write -> barrier.
// Pass order per kc: (ah,bh),(ah,bl),(al,bh) with pass OUTERMOST so consecutive
// MFMAs hit distinct accumulators (no 3-deep same-acc dependency chains).
template<int NT>
__device__ void mfma_layer(__bf16* aHi, __bf16* aLo, const __half* pxh,
    const __bf16* __restrict__ wHi, const __bf16* __restrict__ wLo, int kStr, int nkc,
    const __bf16* __restrict__ xHi, const __bf16* __restrict__ xLo,  // px weights [256][64] or null
    const float* __restrict__ bias, const float* __restrict__ pdW,
    bool relu, int tid) {
  const int wave = tid >> 6, lane = tid & 63;
  const int lm = lane & 15, kq = lane >> 4;
  const int mBase = (wave >> 3) * 64;
  const int nBase = (wave & 7) * (NT * 16);
  f32x4 acc[4][NT];
#pragma unroll
  for (int mt = 0; mt < 4; ++mt)
#pragma unroll
    for (int nt = 0; nt < NT; ++nt)
#pragma unroll
      for (int e = 0; e < 4; ++e) acc[mt][nt][e] = 0.f;

  for (int kc = 0; kc < nkc; ++kc) {           // act part (K = nkc*32)
    const int kb = kc*32 + kq*8;
    bf16x8 ah[4], al[4], bh[NT], bl[NT];
#pragma unroll
    for (int mt = 0; mt < 4; ++mt) {
      const int off = (mBase + mt*16 + lm)*AH + kb;
      ah[mt] = *(const bf16x8*)(aHi + off);
      al[mt] = *(const bf16x8*)(aLo + off);
    }
#pragma unroll
    for (int nt = 0; nt < NT; ++nt) {
      const int ro = (nBase + nt*16 + lm)*kStr + kb;
      bh[nt] = *(const bf16x8*)(wHi + ro);
      bl[nt] = *(const bf16x8*)(wLo + ro);
    }
#pragma unroll
    for (int p = 0; p < 3; ++p)
#pragma unroll
      for (int mt = 0; mt < 4; ++mt)
#pragma unroll
        for (int nt = 0; nt < NT; ++nt)
          acc[mt][nt] = __builtin_amdgcn_mfma_f32_16x16x32_bf16(
              (p == 2) ? al[mt] : ah[mt],
              (p == 1) ? bl[nt] : bh[nt],
              acc[mt][nt], 0, 0, 0);
  }
  if (xHi) {                                   // px part, K=64 (zero-padded tail)
#pragma unroll
    for (int kc = 0; kc < 2; ++kc) {
      const int kb = kc*32 + kq*8;
      bf16x8 ah[4], al[4], bh[NT], bl[NT];
#pragma unroll
      for (int mt = 0; mt < 4; ++mt) {
        const __half* pr = pxh + (mBase + mt*16 + lm)*64 + kb;
#pragma unroll
        for (int j = 0; j < 8; ++j) {
          float v = __half2float(pr[j]);
          __bf16 h = (__bf16)v;
          ah[mt][j] = h;
          al[mt][j] = (__bf16)(v - (float)h);
        }
      }
#pragma unroll
      for (int nt = 0; nt < NT; ++nt) {
        const int ro = (nBase + nt*16 + lm)*64 + kb;
        bh[nt] = *(const bf16x8*)(xHi + ro);
        bl[nt] = *(const bf16x8*)(xLo + ro);
      }
#pragma unroll
      for (int p = 0; p < 3; ++p)
#pragma unroll
        for (int mt = 0; mt < 4; ++mt)
#pragma unroll
          for (int nt = 0; nt < NT; ++nt)
            acc[mt][nt] = __builtin_amdgcn_mfma_f32_16x16x32_bf16(
                (p == 2) ? al[mt] : ah[mt],
                (p == 1) ? bl[nt] : bh[nt],
                acc[mt][nt], 0, 0, 0);
    }
  }
  __syncthreads();                 // all reads of act complete
  // epilogue: C/D mapping row=kq*4+r, col=lm (verified r5 vs r9 bit-match)
#pragma unroll
  for (int mt = 0; mt < 4; ++mt)
#pragma unroll
    for (int nt = 0; nt < NT; ++nt) {
      const int col = nBase + nt*16 + lm;
      float bv = bias[col] + (pdW ? pdW[col] : 0.f);
#pragma unroll
      for (int r = 0; r < 4; ++r) {
        const int row = mBase + mt*16 + kq*4 + r;
        float v = acc[mt][nt][r] + bv;
        if (relu) v = fmaxf(v, 0.f);
        __bf16 h = (__bf16)v;
        aHi[row*AH + col] = h;
        aLo[row*AH + col] = (__bf16)(v - (float)h);
      }
    }
  __syncthreads();
}

__global__ __launch_bounds__(1024, 4) void nerf_main(
    const float* __restrict__ ro, const float* __restrict__ rd, const float* __restrict__ tin,
    const float* __restrict__ b0, const float* __restrict__ bh,
    const float* __restrict__ b5, const float* __restrict__ b6,
    const float* __restrict__ b7,
    const float* __restrict__ Wsig, const float* __restrict__ bs,
    const float* __restrict__ bfb,
    const float* __restrict__ Wm, const float* __restrict__ bm,
    const float* __restrict__ Wr, const float* __restrict__ br,
    const __bf16* __restrict__ wsHi, const __bf16* __restrict__ wsLo,
    float* __restrict__ out) {
  __shared__ __align__(16) __bf16 aHi[128 * AH];       // 67584 B
  __shared__ __align__(16) __bf16 aLo[128 * AH];       // 67584 B
  // pxh (dead after layer 5) unioned with red (first used in sigma head)
  __shared__ __align__(16) unsigned char pxred[16384];
  __shared__ __align__(16) float  pdBuf[24];
  __shared__ __align__(16) float  pdW[128];
  __shared__ __align__(16) float  tBuf[128];
  __shared__ __align__(16) float  sigBuf[128];
  __shared__ __align__(16) float  rgbBuf[128 * 3];

  __half* pxh = (__half*)pxred;        // 128*64 halves = 16384 B
  float*  red = (float*)pxred;         // up to 3*1024 floats = 12288 B (after pxh dead)

  const int b   = blockIdx.x;
  const int tid = threadIdx.x;

  // ---- positional encodings ----
  if (tid < 128) {
    const int m = tid;
    float tv = tin[b*128 + m];
    tBuf[m] = tv;
    float xs[3];
#pragma unroll
    for (int c = 0; c < 3; ++c) xs[c] = ro[b*3 + c] + tv * rd[b*3 + c];
#pragma unroll
    for (int i = 0; i < 10; ++i)
#pragma unroll
      for (int c = 0; c < 3; ++c) {
        float a = ldexpf(xs[c], i);                 // sin(2^i*pi*x) = sinpi(2^i*x)
        pxh[m*64 + i*6 + c]     = __float2half(sinpif(a));
        pxh[m*64 + i*6 + 3 + c] = __float2half(cospif(a));
      }
#pragma unroll
    for (int j = 60; j < 64; ++j) pxh[m*64 + j] = __float2half(0.f);
  } else if (tid < 152) {
    int j = tid - 128;
    int i = j / 6, r = j % 6;
    float a = ldexpf(rd[b*3 + (r % 3)], i);
    pdBuf[j] = (r < 3) ? sinpif(a) : cospif(a);
  }
  __syncthreads();
  if (tid >= 128 && tid < 256) {       // pdW[c] = sum_j pd[j]*Wm[256+j][c]
    int c = tid - 128;
    float s = 0.f;
#pragma unroll
    for (int j = 0; j < 24; ++j) s += pdBuf[j] * Wm[(256 + j)*128 + c];
    pdW[c] = s;
  }
  __syncthreads();

  // ---- trunk ----
  mfma_layer<2>(aHi, aLo, pxh, nullptr, nullptr, 0, 0,
                wsHi + OFF_W0T, wsLo + OFF_W0T, b0, nullptr, true, tid);
  for (int i = 0; i < 4; ++i)
    mfma_layer<2>(aHi, aLo, pxh, wsHi + OFF_WHT + i*65536, wsLo + OFF_WHT + i*65536, 256, 8,
                  nullptr, nullptr, bh + i*256, nullptr, true, tid);
  mfma_layer<2>(aHi, aLo, pxh, wsHi + OFF_W5AT, wsLo + OFF_W5AT, 256, 8,
                wsHi + OFF_W5BT, wsLo + OFF_W5BT, b5, nullptr, true, tid);
  mfma_layer<2>(aHi, aLo, pxh, wsHi + OFF_W6T, wsLo + OFF_W6T, 256, 8,
                nullptr, nullptr, b6, nullptr, true, tid);
  mfma_layer<2>(aHi, aLo, pxh, wsHi + OFF_W7T, wsLo + OFF_W7T, 256, 8,
                nullptr, nullptr, b7, nullptr, true, tid);

  // sigma = relu(h @ Ws + bs): 8 threads per sample over K=256   (pxh now dead)
  {
    const int m = tid >> 3, q = tid & 7;
    float s = 0.f;
    for (int k = q*32; k < q*32 + 32; ++k)
      s += ((float)aHi[m*AH + k] + (float)aLo[m*AH + k]) * Wsig[k];
    red[tid] = s;
    __syncthreads();
    if (tid < 128) {
      float sm = bs[0];
#pragma unroll
      for (int j = 0; j < 8; ++j) sm += red[8*tid + j];
      sigBuf[tid] = fmaxf(sm, 0.f);
    }
    __syncthreads();
  }

  // feat = h @ Wf + bf (no relu)
  mfma_layer<2>(aHi, aLo, nullptr, wsHi + OFF_WFT, wsLo + OFF_WFT, 256, 8,
                nullptr, nullptr, bfb, nullptr, false, tid);

  // h2 = relu([feat, pd] @ Wm + bm), N=128 (pd folded via pdW)
  mfma_layer<1>(aHi, aLo, nullptr, wsHi + OFF_WMAT, wsLo + OFF_WMAT, 256, 8,
                nullptr, nullptr, bm, pdW, true, tid);

  // rgb = sigmoid(h2 @ Wr + br): 8 threads per sample over K=128
  {
    const int m = tid >> 3, q = tid & 7;
    float r0s = 0.f, r1s = 0.f, r2s = 0.f;
    for (int k = q*16; k < q*16 + 16; ++k) {
      float hv = (float)aHi[m*AH + k] + (float)aLo[m*AH + k];
      r0s += hv * Wr[k*3 + 0];
      r1s += hv * Wr[k*3 + 1];
      r2s += hv * Wr[k*3 + 2];
    }
    red[tid] = r0s; red[1024 + tid] = r1s; red[2048 + tid] = r2s;
    __syncthreads();
    if (tid < 128) {
#pragma unroll
      for (int c = 0; c < 3; ++c) {
        float sm = br[c];
#pragma unroll
        for (int j = 0; j < 8; ++j) sm += red[c*1024 + 8*tid + j];
        rgbBuf[tid*3 + c] = 1.f / (1.f + expf(-sm));
      }
    }
    __syncthreads();
  }

  // volume rendering: serial exclusive-transmittance scan
  if (tid == 0) {
    float T = 1.f, c0 = 0.f, c1 = 0.f, c2 = 0.f, wsum = 0.f;
    for (int m = 0; m < 128; ++m) {
      float delta = (m < 127) ? (tBuf[m + 1] - tBuf[m]) : 1e8f;
      float e = expf(-sigBuf[m] * delta);
      float w = T * (1.f - e);
      c0 += w * rgbBuf[m*3 + 0];
      c1 += w * rgbBuf[m*3 + 1];
      c2 += w * rgbBuf[m*3 + 2];
      wsum += w;
      T *= e;
    }
    float bg = 1.f - wsum;               // C_BG = (1,1,1)
    out[b*3 + 0] = c0 + bg;
    out[b*3 + 1] = c1 + bg;
    out[b*3 + 2] = c2 + bg;
  }
}

extern "C" void kernel_launch(void* const* d_in, const int* in_sizes, int n_in,
                              void* d_out, int out_size, void* d_ws, size_t ws_size,
                              hipStream_t stream) {
  const float* ro  = (const float*)d_in[0];
  const float* rd  = (const float*)d_in[1];
  const float* t   = (const float*)d_in[2];
  const float* W0  = (const float*)d_in[3];
  const float* b0  = (const float*)d_in[4];
  const float* Wh  = (const float*)d_in[5];
  const float* bh  = (const float*)d_in[6];
  const float* W5  = (const float*)d_in[7];
  const float* b5  = (const float*)d_in[8];
  const float* W6  = (const float*)d_in[9];
  const float* b6  = (const float*)d_in[10];
  const float* W7  = (const float*)d_in[11];
  const float* b7  = (const float*)d_in[12];
  const float* Wsg = (const float*)d_in[13];
  const float* bs  = (const float*)d_in[14];
  const float* Wf  = (const float*)d_in[15];
  const float* bfb = (const float*)d_in[16];
  const float* Wm  = (const float*)d_in[17];
  const float* bm  = (const float*)d_in[18];
  const float* Wr  = (const float*)d_in[19];
  const float* br  = (const float*)d_in[20];
  float* out = (float*)d_out;

  __bf16* wsHi = (__bf16*)d_ws;        // 2*TOT bf16 = 2.36 MB (proven sufficient)
  __bf16* wsLo = wsHi + TOT;

  prep_weights<<<(TOT + 255)/256, 256, 0, stream>>>(W0, Wh, W5, W6, W7, Wf, Wm, wsHi);
  nerf_main<<<2048, 1024, 0, stream>>>(ro, rd, t, b0, bh, b5, b6, b7,
                                       Wsg, bs, bfb, Wm, bm, Wr, br,
                                       wsHi, wsLo, out);
}

// Round 13
// 1435.220 us; speedup vs baseline: 1.1879x; 1.1879x over previous
//
#include <hip/hip_runtime.h>
#include <hip/hip_fp16.h>
#include <math.h>

typedef __bf16 bf16x8 __attribute__((ext_vector_type(8)));
typedef float  f32x4  __attribute__((ext_vector_type(4)));

#define AH  264              // act plane stride (bf16); 132 dw % 32 == 4 -> 2-way only (free)
#define TOT 589824           // staged weight elems (hi); lo at +TOT

// staged ws layout (bf16, [n][k] transposed, zero-padded K tails)
#define OFF_W0T   0          // [256][64]
#define OFF_WHT   16384      // 4 x [256][256]
#define OFF_W5AT  278528     // [256][256]
#define OFF_W5BT  344064     // [256][64]
#define OFF_W6T   360448     // [256][256]
#define OFF_W7T   425984     // [256][256]
#define OFF_WFT   491520     // [256][256]
#define OFF_WMAT  557056     // [128][256]

__global__ void prep_weights(const float* __restrict__ W0, const float* __restrict__ Wh,
                             const float* __restrict__ W5, const float* __restrict__ W6,
                             const float* __restrict__ W7, const float* __restrict__ Wf,
                             const float* __restrict__ Wm, __bf16* __restrict__ ws) {
  int idx = blockIdx.x * blockDim.x + threadIdx.x;
  if (idx >= TOT) return;
  float v = 0.f;
  if (idx < OFF_WHT)        { int j = idx;            int n=j>>6, k=j&63;   v = (k<60)? W0[k*256+n] : 0.f; }
  else if (idx < OFF_W5AT)  { int j = idx - OFF_WHT;  int i=j>>16, r=j&65535, n=r>>8, k=r&255; v = Wh[i*65536+k*256+n]; }
  else if (idx < OFF_W5BT)  { int j = idx - OFF_W5AT; int n=j>>8, k=j&255;  v = W5[k*256+n]; }
  else if (idx < OFF_W6T)   { int j = idx - OFF_W5BT; int n=j>>6, k=j&63;   v = (k<60)? W5[(256+k)*256+n] : 0.f; }
  else if (idx < OFF_W7T)   { int j = idx - OFF_W6T;  int n=j>>8, k=j&255;  v = W6[k*256+n]; }
  else if (idx < OFF_WFT)   { int j = idx - OFF_W7T;  int n=j>>8, k=j&255;  v = W7[k*256+n]; }
  else if (idx < OFF_WMAT)  { int j = idx - OFF_WFT;  int n=j>>8, k=j&255;  v = Wf[k*256+n]; }
  else                      { int j = idx - OFF_WMAT; int n=j>>8, k=j&255;  v = Wm[k*128+n]; }
  __bf16 hi = (__bf16)v;
  ws[idx] = hi;
  ws[TOT + idx] = (__bf16)(v - (float)hi);
}

// ---- split-bf16 3-pass MFMA layer; act = hi/lo bf16 planes in LDS ----
// 512 threads = 8 waves, 4 m-tiles per wave.
// HALF=1: M=64,  mBase=0,            nBase=wave*(NT*16)    (8 n-groups)
// HALF=0: M=128, mBase=(wave>>2)*64, nBase=(wave&3)*(NT*16) (2x4 groups, r11 cfg)
template<int NT, int HALF>
__device__ void mfma_layer(__bf16* aHi, __bf16* aLo, const __half* pxh,
    const __bf16* __restrict__ wHi, const __bf16* __restrict__ wLo, int kStr, int nkc,
    const __bf16* __restrict__ xHi, const __bf16* __restrict__ xLo,  // px weights or null
    const float* __restrict__ bias, const float* __restrict__ pdW,
    bool relu, int tid) {
  const int wave = tid >> 6, lane = tid & 63;
  const int lm = lane & 15, kq = lane >> 4;
  const int mBase = HALF ? 0 : (wave >> 2) * 64;
  const int nBase = (HALF ? wave : (wave & 3)) * (NT * 16);
  f32x4 acc[4][NT];
#pragma unroll
  for (int mt = 0; mt < 4; ++mt)
#pragma unroll
    for (int nt = 0; nt < NT; ++nt)
#pragma unroll
      for (int e = 0; e < 4; ++e) acc[mt][nt][e] = 0.f;

  for (int kc = 0; kc < nkc; ++kc) {           // act part (K = nkc*32)
    const int kb = kc*32 + kq*8;
    bf16x8 ah[4], al[4], bh[NT], bl[NT];
#pragma unroll
    for (int mt = 0; mt < 4; ++mt) {
      const int off = (mBase + mt*16 + lm)*AH + kb;
      ah[mt] = *(const bf16x8*)(aHi + off);
      al[mt] = *(const bf16x8*)(aLo + off);
    }
#pragma unroll
    for (int nt = 0; nt < NT; ++nt) {
      const int ro = (nBase + nt*16 + lm)*kStr + kb;
      bh[nt] = *(const bf16x8*)(wHi + ro);
      bl[nt] = *(const bf16x8*)(wLo + ro);
    }
#pragma unroll
    for (int p = 0; p < 3; ++p)
#pragma unroll
      for (int mt = 0; mt < 4; ++mt)
#pragma unroll
        for (int nt = 0; nt < NT; ++nt)
          acc[mt][nt] = __builtin_amdgcn_mfma_f32_16x16x32_bf16(
              (p == 2) ? al[mt] : ah[mt],
              (p == 1) ? bl[nt] : bh[nt],
              acc[mt][nt], 0, 0, 0);
  }
  if (xHi) {                                   // px part, K=64 (zero-padded tail)
#pragma unroll
    for (int kc = 0; kc < 2; ++kc) {
      const int kb = kc*32 + kq*8;
      bf16x8 ah[4], al[4], bh[NT], bl[NT];
#pragma unroll
      for (int mt = 0; mt < 4; ++mt) {
        const __half* pr = pxh + (mBase + mt*16 + lm)*64 + kb;
#pragma unroll
        for (int j = 0; j < 8; ++j) {
          float v = __half2float(pr[j]);
          __bf16 h = (__bf16)v;
          ah[mt][j] = h;
          al[mt][j] = (__bf16)(v - (float)h);
        }
      }
#pragma unroll
      for (int nt = 0; nt < NT; ++nt) {
        const int ro = (nBase + nt*16 + lm)*64 + kb;
        bh[nt] = *(const bf16x8*)(xHi + ro);
        bl[nt] = *(const bf16x8*)(xLo + ro);
      }
#pragma unroll
      for (int p = 0; p < 3; ++p)
#pragma unroll
        for (int mt = 0; mt < 4; ++mt)
#pragma unroll
          for (int nt = 0; nt < NT; ++nt)
            acc[mt][nt] = __builtin_amdgcn_mfma_f32_16x16x32_bf16(
                (p == 2) ? al[mt] : ah[mt],
                (p == 1) ? bl[nt] : bh[nt],
                acc[mt][nt], 0, 0, 0);
    }
  }
  __syncthreads();                 // all reads of act complete
#pragma unroll
  for (int mt = 0; mt < 4; ++mt)
#pragma unroll
    for (int nt = 0; nt < NT; ++nt) {
      const int col = nBase + nt*16 + lm;
      float bv = bias[col] + (pdW ? pdW[col] : 0.f);
#pragma unroll
      for (int r = 0; r < 4; ++r) {
        const int row = mBase + mt*16 + kq*4 + r;
        float v = acc[mt][nt][r] + bv;
        if (relu) v = fmaxf(v, 0.f);
        __bf16 h = (__bf16)v;
        aHi[row*AH + col] = h;
        aLo[row*AH + col] = (__bf16)(v - (float)h);
      }
    }
  __syncthreads();
}

// HALF=1: blockIdx = ray*2 + half, covers samples [half*64, half*64+64)
// HALF=0: blockIdx = ray, covers all 128 samples (fallback, r11 config)
template<int HALF>
__global__ __launch_bounds__(512, 4) void nerf_main(
    const float* __restrict__ ro, const float* __restrict__ rd, const float* __restrict__ tin,
    const float* __restrict__ b0, const float* __restrict__ bh,
    const float* __restrict__ b5, const float* __restrict__ b6,
    const float* __restrict__ b7,
    const float* __restrict__ Wsig, const float* __restrict__ bs,
    const float* __restrict__ bfb,
    const float* __restrict__ Wm, const float* __restrict__ bm,
    const float* __restrict__ Wr, const float* __restrict__ br,
    const __bf16* __restrict__ wsHi, const __bf16* __restrict__ wsLo,
    float* __restrict__ part, float* __restrict__ out) {
  constexpr int M = HALF ? 64 : 128;
  __shared__ __align__(16) __bf16 aHi[M * AH];
  __shared__ __align__(16) __bf16 aLo[M * AH];
  __shared__ __align__(16) unsigned char pxred[M * 128];  // pxh (M*64 halves) / red union
  __shared__ __align__(16) float  pdBuf[24];
  __shared__ __align__(16) float  pdW[128];
  __shared__ __align__(16) float  tBuf[M + 4];
  __shared__ __align__(16) float  sigBuf[M];
  __shared__ __align__(16) float  rgbBuf[M * 3];

  __half* pxh = (__half*)pxred;
  float*  red = (float*)pxred;         // used after pxh dead (sigma head onward)

  const int blk  = blockIdx.x;
  const int ray  = HALF ? (blk >> 1) : blk;
  const int S    = HALF ? (blk & 1) * 64 : 0;
  const int tid  = threadIdx.x;

  // ---- positional encodings ----
  if (tid < M) {
    const int m = tid;
    float tv = tin[ray*128 + S + m];
    tBuf[m] = tv;
    float xs[3];
#pragma unroll
    for (int c = 0; c < 3; ++c) xs[c] = ro[ray*3 + c] + tv * rd[ray*3 + c];
#pragma unroll
    for (int i = 0; i < 10; ++i)
#pragma unroll
      for (int c = 0; c < 3; ++c) {
        float a = ldexpf(xs[c], i);                 // sin(2^i*pi*x) = sinpi(2^i*x)
        pxh[m*64 + i*6 + c]     = __float2half(sinpif(a));
        pxh[m*64 + i*6 + 3 + c] = __float2half(cospif(a));
      }
#pragma unroll
    for (int j = 60; j < 64; ++j) pxh[m*64 + j] = __float2half(0.f);
  } else if (tid < M + 24) {
    int j = tid - M;
    int i = j / 6, r = j % 6;
    float a = ldexpf(rd[ray*3 + (r % 3)], i);
    pdBuf[j] = (r < 3) ? sinpif(a) : cospif(a);
  } else if (tid == M + 24) {
    tBuf[M] = (S + M < 128) ? tin[ray*128 + S + M] : 0.f;   // next-t for last delta
  }
  __syncthreads();
  if (tid >= 256 && tid < 384) {       // pdW[c] = sum_j pd[j]*Wm[256+j][c]
    int c = tid - 256;
    float s = 0.f;
#pragma unroll
    for (int j = 0; j < 24; ++j) s += pdBuf[j] * Wm[(256 + j)*128 + c];
    pdW[c] = s;
  }
  __syncthreads();

  constexpr int NTF = HALF ? 2 : 4;    // full layers (N=256)
  constexpr int NTW = HALF ? 1 : 2;    // Wm layer (N=128)

  // ---- trunk ----
  mfma_layer<NTF, HALF>(aHi, aLo, pxh, nullptr, nullptr, 0, 0,
                        wsHi + OFF_W0T, wsLo + OFF_W0T, b0, nullptr, true, tid);
  for (int i = 0; i < 4; ++i)
    mfma_layer<NTF, HALF>(aHi, aLo, pxh, wsHi + OFF_WHT + i*65536, wsLo + OFF_WHT + i*65536, 256, 8,
                          nullptr, nullptr, bh + i*256, nullptr, true, tid);
  mfma_layer<NTF, HALF>(aHi, aLo, pxh, wsHi + OFF_W5AT, wsLo + OFF_W5AT, 256, 8,
                        wsHi + OFF_W5BT, wsLo + OFF_W5BT, b5, nullptr, true, tid);
  mfma_layer<NTF, HALF>(aHi, aLo, pxh, wsHi + OFF_W6T, wsLo + OFF_W6T, 256, 8,
                        nullptr, nullptr, b6, nullptr, true, tid);
  mfma_layer<NTF, HALF>(aHi, aLo, pxh, wsHi + OFF_W7T, wsLo + OFF_W7T, 256, 8,
                        nullptr, nullptr, b7, nullptr, true, tid);

  // sigma = relu(h @ Ws + bs)   (pxh now dead -> red)
  {
    constexpr int TPS = 512 / M;       // threads per sample (8 or 4)
    const int m = tid / TPS, q = tid % TPS;
    const int kn = 256 / TPS;
    float s = 0.f;
    for (int k = q*kn; k < q*kn + kn; ++k)
      s += ((float)aHi[m*AH + k] + (float)aLo[m*AH + k]) * Wsig[k];
    red[tid] = s;
    __syncthreads();
    if (tid < M) {
      float sm = bs[0];
#pragma unroll
      for (int j = 0; j < TPS; ++j) sm += red[TPS*tid + j];
      sigBuf[tid] = fmaxf(sm, 0.f);
    }
    __syncthreads();
  }

  // feat = h @ Wf + bf (no relu)
  mfma_layer<NTF, HALF>(aHi, aLo, nullptr, wsHi + OFF_WFT, wsLo + OFF_WFT, 256, 8,
                        nullptr, nullptr, bfb, nullptr, false, tid);

  // h2 = relu([feat, pd] @ Wm + bm), N=128 (pd folded via pdW)
  mfma_layer<NTW, HALF>(aHi, aLo, nullptr, wsHi + OFF_WMAT, wsLo + OFF_WMAT, 256, 8,
                        nullptr, nullptr, bm, pdW, true, tid);

  // rgb = sigmoid(h2 @ Wr + br)
  {
    constexpr int TPS = 512 / M;
    const int m = tid / TPS, q = tid % TPS;
    const int kn = 128 / TPS;
    float r0s = 0.f, r1s = 0.f, r2s = 0.f;
    for (int k = q*kn; k < q*kn + kn; ++k) {
      float hv = (float)aHi[m*AH + k] + (float)aLo[m*AH + k];
      r0s += hv * Wr[k*3 + 0];
      r1s += hv * Wr[k*3 + 1];
      r2s += hv * Wr[k*3 + 2];
    }
    red[tid] = r0s; red[512 + tid] = r1s; red[1024 + tid] = r2s;
    __syncthreads();
    if (tid < M) {
#pragma unroll
      for (int c = 0; c < 3; ++c) {
        float sm = br[c];
#pragma unroll
        for (int j = 0; j < TPS; ++j) sm += red[c*512 + TPS*tid + j];
        rgbBuf[tid*3 + c] = 1.f / (1.f + expf(-sm));
      }
    }
    __syncthreads();
  }

  // volume rendering: serial transmittance scan over this block's segment
  if (tid == 0) {
    float T = 1.f, c0 = 0.f, c1 = 0.f, c2 = 0.f, wsum = 0.f;
    for (int m = 0; m < M; ++m) {
      float delta = (S + m < 127) ? (tBuf[m + 1] - tBuf[m]) : 1e8f;
      float e = expf(-sigBuf[m] * delta);
      float w = T * (1.f - e);
      c0 += w * rgbBuf[m*3 + 0];
      c1 += w * rgbBuf[m*3 + 1];
      c2 += w * rgbBuf[m*3 + 2];
      wsum += w;
      T *= e;
    }
    if (HALF) {
      float* p = part + blk*5;
      p[0] = c0; p[1] = c1; p[2] = c2; p[3] = wsum; p[4] = T;
    } else {
      float bg = 1.f - wsum;           // C_BG = (1,1,1)
      out[ray*3 + 0] = c0 + bg;
      out[ray*3 + 1] = c1 + bg;
      out[ray*3 + 2] = c2 + bg;
    }
  }
}

__global__ void combine(const float* __restrict__ part, float* __restrict__ out) {
  int r = blockIdx.x * blockDim.x + threadIdx.x;
  if (r >= 2048) return;
  const float* p0 = part + (2*r)*5;
  const float* p1 = p0 + 5;
  float T0 = p0[4];
  float wsum = p0[3] + T0 * p1[3];
  float bg = 1.f - wsum;               // C_BG = (1,1,1)
#pragma unroll
  for (int c = 0; c < 3; ++c)
    out[r*3 + c] = p0[c] + T0 * p1[c] + bg;
}

extern "C" void kernel_launch(void* const* d_in, const int* in_sizes, int n_in,
                              void* d_out, int out_size, void* d_ws, size_t ws_size,
                              hipStream_t stream) {
  const float* ro  = (const float*)d_in[0];
  const float* rd  = (const float*)d_in[1];
  const float* t   = (const float*)d_in[2];
  const float* W0  = (const float*)d_in[3];
  const float* b0  = (const float*)d_in[4];
  const float* Wh  = (const float*)d_in[5];
  const float* bh  = (const float*)d_in[6];
  const float* W5  = (const float*)d_in[7];
  const float* b5  = (const float*)d_in[8];
  const float* W6  = (const float*)d_in[9];
  const float* b6  = (const float*)d_in[10];
  const float* W7  = (const float*)d_in[11];
  const float* b7  = (const float*)d_in[12];
  const float* Wsg = (const float*)d_in[13];
  const float* bs  = (const float*)d_in[14];
  const float* Wf  = (const float*)d_in[15];
  const float* bfb = (const float*)d_in[16];
  const float* Wm  = (const float*)d_in[17];
  const float* bm  = (const float*)d_in[18];
  const float* Wr  = (const float*)d_in[19];
  const float* br  = (const float*)d_in[20];
  float* out = (float*)d_out;

  __bf16* wsHi = (__bf16*)d_ws;                     // 2*TOT bf16 = 2.36 MB (proven)
  __bf16* wsLo = wsHi + TOT;
  float*  part = (float*)((char*)d_ws + (size_t)2 * TOT * 2);   // 4096*5 floats = 80 KB

  const size_t needSplit = (size_t)2 * TOT * 2 + (size_t)4096 * 5 * 4;

  prep_weights<<<(TOT + 255)/256, 256, 0, stream>>>(W0, Wh, W5, W6, W7, Wf, Wm, wsHi);
  if (ws_size >= needSplit) {
    nerf_main<1><<<4096, 512, 0, stream>>>(ro, rd, t, b0, bh, b5, b6, b7,
                                           Wsg, bs, bfb, Wm, bm, Wr, br,
                                           wsHi, wsLo, part, out);
    combine<<<8, 256, 0, stream>>>(part, out);
  } else {
    nerf_main<0><<<2048, 512, 0, stream>>>(ro, rd, t, b0, bh, b5, b6, b7,
                                           Wsg, bs, bfb, Wm, bm, Wr, br,
                                           wsHi, wsLo, part, out);
  }
}